// Round 2
// baseline (1342.118 us; speedup 1.0000x reference)
//
#include <hip/hip_runtime.h>
#include <cstddef>

#define KH   3
#define KW   3
#define DIL  2
#define GRP  4
#define CIN  256
#define COUT 256
#define OCH  72      // offset channels = G*K*2
#define HIN  132
#define WIN  132
#define HO   128
#define WO   128
#define CG   64      // channels per group
#define KKT  9       // taps

// ---------------------------------------------------------------------------
// Kernel 1: offset conv — direct dilated 3x3 conv, 256->72 ch, VALID, dil=2.
// Grid 512 = (n, y, half-row of 64 px). Block 512 thr = 8 waves.
//   wave w handles oc set [w*9, w*9+9); lane = px. acc[9] in VGPR.
//   weights wave-uniform -> s_load; x staged 4 channels/round in LDS.
// ---------------------------------------------------------------------------
__global__ __launch_bounds__(512)
void offset_conv_kernel(const float* __restrict__ x,
                        const float* __restrict__ w,
                        const float* __restrict__ b,
                        float* __restrict__ off) {
    const int bid = blockIdx.x;            // n(2) * y(128) * half(2)
    const int xh  = bid & 1;
    const int y   = (bid >> 1) & 127;
    const int n   = bid >> 8;
    const int px0 = xh * 64;

    const int t    = threadIdx.x;
    const int px   = t & 63;
    const int oset = __builtin_amdgcn_readfirstlane(t >> 6);   // 0..7 wave-uniform

    __shared__ float xs[4][3][68];         // 4 ch x 3 rows x 68 cols, 3264 B

    float acc[9];
#pragma unroll
    for (int i = 0; i < 9; ++i) acc[i] = 0.f;

    const float* xn = x + (size_t)n * CIN * HIN * WIN;

#pragma unroll 1
    for (int c0 = 0; c0 < CIN; c0 += 4) {
        __syncthreads();
#pragma unroll
        for (int i = 0; i < 2; ++i) {       // 816 = 4*3*68 elements
            int s = t + i * 512;
            if (s < 816) {
                int c  = s / 204;
                int rr = s - 204 * c;
                int r  = rr / 68;
                int cc = rr - 68 * r;
                xs[c][r][cc] = xn[(size_t)(c0 + c) * (HIN * WIN) + (y + 2 * r) * WIN + px0 + cc];
            }
        }
        __syncthreads();

#pragma unroll
        for (int c = 0; c < 4; ++c) {
            float xr[9];
#pragma unroll
            for (int ky = 0; ky < 3; ++ky)
#pragma unroll
                for (int kx = 0; kx < 3; ++kx)
                    xr[ky * 3 + kx] = xs[c][ky][px + 2 * kx];

            const float* wc = w + ((size_t)(oset * 9) * CIN + (c0 + c)) * KKT;
#pragma unroll
            for (int o = 0; o < 9; ++o) {
                const float* wo = wc + (size_t)o * (CIN * KKT);  // wave-uniform -> s_load
#pragma unroll
                for (int j = 0; j < 9; ++j)
                    acc[o] = fmaf(wo[j], xr[j], acc[o]);
            }
        }
    }

#pragma unroll
    for (int o = 0; o < 9; ++o) {
        int oc = oset * 9 + o;
        off[((size_t)(n * OCH + oc) * HO + y) * WO + px0 + px] = acc[o] + b[oc];
    }
}

// ---------------------------------------------------------------------------
// Kernel 2: deformable conv.
// Grid 512 = (n, y, half-row 64 px). Block 512 thr = 8 waves.
//   GEMM phase: wave = 32 oc (oc_base = wave*32), lane = px. acc[32] VGPR.
//   Per group g: bilinear weights + precomputed gather offsets -> LDS (SoA,
//   conflict-free); channels staged 4-at-a-time: smp[4][9][64] im2col tile.
//   Deform weights wave-uniform -> SGPR (36 contiguous floats per oc/chunk).
// ---------------------------------------------------------------------------
__global__ __launch_bounds__(512)
void deform_kernel(const float* __restrict__ x,
                   const float* __restrict__ off,
                   const float* __restrict__ dw,
                   float* __restrict__ out) {
    const int bid = blockIdx.x;
    const int xh  = bid & 1;
    const int y   = (bid >> 1) & 127;
    const int n   = bid >> 8;
    const int px0 = xh * 64;

    const int t       = threadIdx.x;
    const int px      = t & 63;
    const int oc_base = __builtin_amdgcn_readfirstlane(t >> 6) * 32;

    __shared__ float cw[4][KKT][64];       // bilinear corner weights, 9216 B
    __shared__ int   ci[4][KKT][64];       // precomputed gather offsets, 9216 B
    __shared__ float smp[4][KKT][64];      // sampled im2col tile, 9216 B

    float acc[32];
#pragma unroll
    for (int i = 0; i < 32; ++i) acc[i] = 0.f;

#pragma unroll 1
    for (int g = 0; g < GRP; ++g) {
        __syncthreads();                    // protect cw/ci from prior staging reads
        // ---- bilinear coefficients for this group: 9 taps x 64 px ----
#pragma unroll
        for (int i = 0; i < 2; ++i) {       // 576 elements
            int s = t + i * 512;
            if (s < KKT * 64) {
                int k  = s >> 6;
                int pp = s & 63;
                int ky = k / 3, kx = k - ky * 3;
                size_t obase = ((size_t)(n * OCH + g * 18 + k * 2) * HO + y) * WO + px0 + pp;
                float dy = off[obase];
                float dx = off[obase + (size_t)HO * WO];
                float fy = dy + (float)(ky * DIL + y);
                float fx = dx + (float)(kx * DIL + px0 + pp);
                float y0f = floorf(fy), x0f = floorf(fx);
                float ly = fy - y0f,   lx = fx - x0f;
                int iy0 = (int)y0f, ix0 = (int)x0f;
                int iy1 = iy0 + 1,  ix1 = ix0 + 1;
                float vy0 = (iy0 >= 0 && iy0 < HIN) ? 1.f : 0.f;
                float vy1 = (iy1 >= 0 && iy1 < HIN) ? 1.f : 0.f;
                float vx0 = (ix0 >= 0 && ix0 < WIN) ? 1.f : 0.f;
                float vx1 = (ix1 >= 0 && ix1 < WIN) ? 1.f : 0.f;
                int iy0c = min(max(iy0, 0), HIN - 1);
                int iy1c = min(max(iy1, 0), HIN - 1);
                int ix0c = min(max(ix0, 0), WIN - 1);
                int ix1c = min(max(ix1, 0), WIN - 1);
                cw[0][k][pp] = (1.f - ly) * (1.f - lx) * vy0 * vx0;
                cw[1][k][pp] = (1.f - ly) * lx * vy0 * vx1;
                cw[2][k][pp] = ly * (1.f - lx) * vy1 * vx0;
                cw[3][k][pp] = ly * lx * vy1 * vx1;
                ci[0][k][pp] = iy0c * WIN + ix0c;
                ci[1][k][pp] = iy0c * WIN + ix1c;
                ci[2][k][pp] = iy1c * WIN + ix0c;
                ci[3][k][pp] = iy1c * WIN + ix1c;
            }
        }
        __syncthreads();

#pragma unroll 1
        for (int chk = 0; chk < CG / 4; ++chk) {
            const int c0 = chk * 4;
            // ---- stage sampled im2col tile: 4 ch x 9 taps x 64 px = 2304 ----
#pragma unroll
            for (int i = 0; i < 5; ++i) {
                int s = t + i * 512;
                if (s < 2304) {
                    int pp = s & 63;
                    int r  = s >> 6;               // 0..35
                    int k  = r % 9;
                    int c  = r / 9;                // 0..3
                    const float* xb = x + (size_t)(n * CIN + g * CG + c0 + c) * (HIN * WIN);
                    smp[c][k][pp] = cw[0][k][pp] * xb[ci[0][k][pp]]
                                  + cw[1][k][pp] * xb[ci[1][k][pp]]
                                  + cw[2][k][pp] * xb[ci[2][k][pp]]
                                  + cw[3][k][pp] * xb[ci[3][k][pp]];
                }
            }
            __syncthreads();

            // ---- GEMM: acc[o] += sum_{c4,k9} smp * w ----
            float sv[36];
#pragma unroll
            for (int c = 0; c < 4; ++c)
#pragma unroll
                for (int k = 0; k < 9; ++k)
                    sv[c * 9 + k] = smp[c][k][px];

            const float* wb = dw + ((size_t)oc_base * CIN + g * CG + c0) * KKT;
#pragma unroll
            for (int o = 0; o < 32; ++o) {
                const float* wr = wb + (size_t)o * (CIN * KKT);  // wave-uniform -> s_load
#pragma unroll
                for (int j = 0; j < 36; ++j)
                    acc[o] = fmaf(wr[j], sv[j], acc[o]);
            }
            __syncthreads();                // smp/cw/ci consumed before next stage
        }
    }

    // ---- epilogue: coalesced stores, 32 output channels per thread ----
#pragma unroll
    for (int o = 0; o < 32; ++o) {
        out[((size_t)(n * COUT + oc_base + o) * HO + y) * WO + px0 + px] = acc[o];
    }
}

// ---------------------------------------------------------------------------
extern "C" void kernel_launch(void* const* d_in, const int* in_sizes, int n_in,
                              void* d_out, int out_size, void* d_ws, size_t ws_size,
                              hipStream_t stream) {
    const float* x  = (const float*)d_in[0];   // (2,256,132,132)
    const float* ow = (const float*)d_in[1];   // (72,256,3,3)
    const float* ob = (const float*)d_in[2];   // (72,)
    const float* dw = (const float*)d_in[3];   // (256,256,3,3)
    float* out = (float*)d_out;                // (2,256,128,128)
    float* off = (float*)d_ws;                 // (2,72,128,128) scratch: 9.4 MB

    offset_conv_kernel<<<512, 512, 0, stream>>>(x, ow, ob, off);
    deform_kernel<<<512, 512, 0, stream>>>(x, off, dw, out);
}